// Round 13
// baseline (157.190 us; speedup 1.0000x reference)
//
#include <hip/hip_runtime.h>
#include <hip/hip_bf16.h>
#include <math.h>

// ---------------------------------------------------------------------------
// LowRankSparseAttention on MI355X (gfx950)
//   1. prep: cvt resid->A_bf, cvt W_V->Wt rows 2048+, virtual K/V fills,
//      transpose W_Q/W_K->Wt, transpose W_O->Wot
//   2. gemm1_fused: 256x128 tile, 8 waves, BK=64, TRIPLE-BUFFERED
//      FINE-PHASED pipeline (T3+T4 on the R10-verified skeleton):
//      per K-tile, 2 phases of {8 ds_read_b128 + stage-issues for t+2
//      -> setprio(1) 16 MFMA setprio(0) -> s_barrier}; counted vmcnt(6)
//      once per tile (never 0 in main loop). 3rd buffer makes in-phase
//      stage issues race-free (readers of buf[(t+2)%3] finished at the
//      end-of-(t-1) barrier). R10's coarse variant = m196's measured
//      failure mode; this is the fine interleave m196/m218 measured as
//      the actual lever. LDS 144KB -> 1 block/CU, grid 256.
//      Fused epilogue byte-identical to R10 (correctness-verified).
//   3. attn_mfma: PAIRED-TILE flash attn: wave owns tiles x and 63-x,
//      K-fragments + V ping-pong LDS staging shared across chains;
//      FIXED-MAX softmax (m=0 exact, scores O(0.4)); exp2 via
//      __builtin_amdgcn_exp2f; per-lane partial l, one reduce at end.
//   4. gemm2 (64x64 tile, BK=128, double-buffered prefetch, 512 blocks,
//      XCD supertile; compile-time K/ldc + hoisted staging bases).
// 128-B LDS rows (8 chunks) alias banks -> staging XOR-swizzles source
// chunks (g = j ^ (row&7)); frag reads un-swizzle -> 2-way conflicts (free).
// Session note: ~44us of measured dur is the harness's 268MB workspace
// poison fill (75% HBM peak, per-iteration) — irreducible from kernel code.
// ---------------------------------------------------------------------------

typedef short bf16x8 __attribute__((ext_vector_type(8)));
typedef short short4v __attribute__((ext_vector_type(4)));
typedef float f32x4 __attribute__((ext_vector_type(4)));
typedef int int4v __attribute__((ext_vector_type(4)));
typedef __hip_bfloat16 bf16;

#define AS1(p) ((const __attribute__((address_space(1))) void*)(const void*)(p))
#define AS3(p) ((__attribute__((address_space(3))) void*)(void*)(p))

static constexpr float INV_SCALE = 0.17677669529663687f;          // 1/sqrt(32)
static constexpr float INV_SCALE_LG2E =
    0.17677669529663687f * 1.4426950408889634f;                   // /sqrt(32)*log2(e)

// fast RNE f32->bf16 (finite values only): 4 int ops
__device__ inline short rnd_bf16(float x) {
  unsigned u = __float_as_uint(x);
  return (short)((u + 0x7fffu + ((u >> 16) & 1u)) >> 16);
}

// pack two positive f32 -> dword of bf16 pair (round half-up)
__device__ inline int pack_bf16_pair(float hi, float lo) {
  unsigned a = __float_as_uint(hi) + 0x8000u;
  unsigned b = __float_as_uint(lo) + 0x8000u;
  return (int)__builtin_amdgcn_perm(a, b, 0x07060302u);
}

// ---- merged preprocessing kernel ------------------------------------------
__global__ __launch_bounds__(256) void prep(
    const float* __restrict__ resid, const float* __restrict__ WV,
    const float* __restrict__ WQ, const float* __restrict__ WK,
    const float* __restrict__ WO, const float* __restrict__ vk,
    const float* __restrict__ vv,
    bf16* __restrict__ A_bf, bf16* __restrict__ Wt, bf16* __restrict__ Wot,
    bf16* __restrict__ Kb, bf16* __restrict__ Vb) {
  __shared__ float t[64][65];
  const int blk = blockIdx.x, tid = threadIdx.x;
  if (blk < 4096) {
    const float* src = (blk < 2048) ? resid : WV;
    short* dst = (short*)((blk < 2048) ? A_bf : (Wt + (size_t)2048 * 1024));
    int i = ((blk & 2047) * 256 + tid) * 4;
    float4 v = *(const float4*)(src + i);
    dst[i + 0] = rnd_bf16(v.x); dst[i + 1] = rnd_bf16(v.y);
    dst[i + 2] = rnd_bf16(v.z); dst[i + 3] = rnd_bf16(v.w);
  } else if (blk < 7168) {
    int idx = (blk - 4096) * 256 + tid;
    if (idx < 262144) {              // Kb virtual: toks 1024..1151 per (b,h)
      int b = idx >> 17, rem = idx & 131071;
      int j = rem >> 10, c = rem & 1023;     // c = h*32+d
      int h = c >> 5, d = c & 31;
      float v = (j < 16) ? vk[j * 1024 + c] : 0.f;
      Kb[(((size_t)(b * 32 + h)) * 1152 + 1024 + j) * 32 + d] = __float2bfloat16(v);
    } else if (idx < 524288) {       // Vb virtual: chunk 16 (toks 1024..1087)
      int i2 = idx - 262144;         // [0, 262144): 2 b x 2048 ch x 64 p
      int b = i2 >> 17, rem = i2 & 131071;
      int ch = rem >> 6, p = rem & 63;
      int pl = p & 31;
      int u = (p & 32) | ((pl & 4) << 2) | ((pl & 24) >> 1) | (pl & 3);
      float v = (u < 16) ? vv[(size_t)u * 2048 + ch] : 0.f;
      int hv = ch >> 6, c = ch & 63;
      int slot = c * 8 + ((p >> 3) ^ (c & 7));
      Vb[((((size_t)(b * 32 + hv)) * 17 + 16) * 512 + slot) * 8 + (p & 7)] = __float2bfloat16(v);
    }
  } else if (blk < 8192) {
    int i = blk - 7168;
    int mt = i & 15, h = (i >> 4) & 31, qk = i >> 9;
    const float* W = qk ? WK : WQ;
    const int m0 = mt * 64;
    for (int idx = tid; idx < 64 * 32; idx += 256) {
      int ii = idx >> 5, d = idx & 31;
      t[ii][d] = W[((size_t)h * 1024 + m0 + ii) * 32 + d];
    }
    __syncthreads();
    const int rowbase = qk * 1024 + h * 32;
    for (int idx = tid; idx < 32 * 64; idx += 256) {
      int d = idx >> 6, ii = idx & 63;
      Wt[(size_t)(rowbase + d) * 1024 + m0 + ii] = __float2bfloat16(t[ii][d]);
    }
  } else {
    int i = blk - 8192;
    int h0 = (i & 31) * 64, m0 = (i >> 5) * 64;
    for (int idx = tid; idx < 64 * 64; idx += 256) {
      int ii = idx >> 6, j = idx & 63;
      t[ii][j] = WO[(size_t)(h0 + ii) * 1024 + m0 + j];
    }
    __syncthreads();
    for (int idx = tid; idx < 64 * 64; idx += 256) {
      int ii = idx >> 6, j = idx & 63;
      Wot[(size_t)(m0 + ii) * 2048 + h0 + j] = __float2bfloat16(t[j][ii]);
    }
  }
}

// ---- GEMM1 + fused epilogue: 256x128 tile, 8 waves, BK=64, K=1024 ---------
// Fine-phased triple-buffered pipeline. Per K-tile t (buffers mod 3):
//   phase0: ds_read ks=0 frags; issue 4 A-stages for t+2 into buf[(t+2)%3];
//           setprio(1) 16 MFMA setprio(0); s_barrier
//   phase1: ds_read ks=1 frags; issue 2 B-stages for t+2;
//           setprio(1) 16 MFMA setprio(0); vmcnt(6) [t+1 landed, t+2's 6
//           in flight]; s_barrier
// Race-free: buf[(t+2)%3]'s readers (tile t-1) all passed the end-of-(t-1)
// barrier before tile t's stage issues. LDS 144KB -> 1 block/CU, grid 256.
// Rows 128B (8 chunks); source pre-swizzle g=j^(row&7), reads un-swizzle.
__global__ __launch_bounds__(512) void gemm1_fused(
    const bf16* __restrict__ A, const bf16* __restrict__ Bt,
    const float* __restrict__ bQ, const float* __restrict__ bK,
    const float* __restrict__ bV,
    bf16* __restrict__ Qb, bf16* __restrict__ Kb, bf16* __restrict__ Vb) {
  __shared__ __align__(16) short As[3][256 * 64];
  __shared__ __align__(16) short Bs[3][128 * 64];
  const int flat = blockIdx.x;
  const int xcd = flat & 7, idx = flat >> 3;            // idx 0..31
  const int tileM = ((xcd >> 2) * 4 + (idx & 3)) * 256; // 8 M-tiles
  const int tileN = ((xcd & 3) * 8 + (idx >> 2)) * 128; // 32 N-tiles
  const int tid = threadIdx.x, wave = tid >> 6, lane = tid & 63;
  const int wm = (wave >> 1) * 64, wn = (wave & 1) * 64;
  const int mrow = lane & 15, kq = lane >> 4;
  const bool isQK = tileN < 2048;
  f32x4 acc[4][4] = {};

  // loop-invariant staging sources (row & swizzle fixed per thread)
  const short* gaB[4];
  const short* gbB[2];
#pragma unroll
  for (int i = 0; i < 4; i++) {
    int c = (wave * 4 + i) * 64 + lane;        // A chunk 0..2047
    int row = c >> 3, g = (c & 7) ^ (row & 7);
    gaB[i] = (const short*)A + (size_t)(tileM + row) * 1024 + g * 8;
  }
#pragma unroll
  for (int i = 0; i < 2; i++) {
    int c = (wave * 2 + i) * 64 + lane;        // B chunk 0..1023
    int row = c >> 3, g = (c & 7) ^ (row & 7);
    gbB[i] = (const short*)Bt + (size_t)(tileN + row) * 1024 + g * 8;
  }

#define G1_STAGE_A(buf, k0)                                                   \
  {                                                                           \
    _Pragma("unroll")                                                         \
    for (int i = 0; i < 4; i++)                                               \
      __builtin_amdgcn_global_load_lds(AS1(gaB[i] + (k0)),                    \
          AS3(&As[buf][(wave * 4 + i) * 512]), 16, 0, 0);                     \
  }
#define G1_STAGE_B(buf, k0)                                                   \
  {                                                                           \
    _Pragma("unroll")                                                         \
    for (int i = 0; i < 2; i++)                                               \
      __builtin_amdgcn_global_load_lds(AS1(gbB[i] + (k0)),                    \
          AS3(&Bs[buf][(wave * 2 + i) * 512]), 16, 0, 0);                     \
  }

  // prologue: stage tiles 0 and 1 (6 loads each, interleaved A+B per tile)
  G1_STAGE_A(0, 0);  G1_STAGE_B(0, 0);
  G1_STAGE_A(1, 64); G1_STAGE_B(1, 64);
  asm volatile("s_waitcnt vmcnt(6)" ::: "memory");   // tile0's 6 landed
  asm volatile("s_barrier" ::: "memory");

  int cur = 0, nxt2 = 2;
  for (int t = 0; t < 16; ++t) {
    const short* as = &As[cur][0];
    const short* bs = &Bs[cur][0];
    // ---- phase 0: ks=0 ----
    {
      bf16x8 af[4], bfr[4];
#pragma unroll
      for (int t2 = 0; t2 < 4; t2++) {
        int ra = wm + t2 * 16 + mrow, rb = wn + t2 * 16 + mrow;
        af[t2]  = *(const bf16x8*)&as[ra * 64 + (kq ^ (ra & 7)) * 8];
        bfr[t2] = *(const bf16x8*)&bs[rb * 64 + (kq ^ (rb & 7)) * 8];
      }
      if (t + 2 < 16) G1_STAGE_A(nxt2, (t + 2) << 6);
      __builtin_amdgcn_s_setprio(1);
      if (isQK) {
#pragma unroll
        for (int fj = 0; fj < 4; fj++)
#pragma unroll
          for (int ti = 0; ti < 4; ti++)
            acc[fj][ti] = __builtin_amdgcn_mfma_f32_16x16x32_bf16(bfr[fj], af[ti], acc[fj][ti], 0, 0, 0);
      } else {
#pragma unroll
        for (int i = 0; i < 4; i++)
#pragma unroll
          for (int j = 0; j < 4; j++)
            acc[i][j] = __builtin_amdgcn_mfma_f32_16x16x32_bf16(af[i], bfr[j], acc[i][j], 0, 0, 0);
      }
      __builtin_amdgcn_s_setprio(0);
    }
    asm volatile("s_barrier" ::: "memory");
    // ---- phase 1: ks=1 ----
    {
      bf16x8 af[4], bfr[4];
#pragma unroll
      for (int t2 = 0; t2 < 4; t2++) {
        int ra = wm + t2 * 16 + mrow, rb = wn + t2 * 16 + mrow;
        af[t2]  = *(const bf16x8*)&as[ra * 64 + ((4 + kq) ^ (ra & 7)) * 8];
        bfr[t2] = *(const bf16x8*)&bs[rb * 64 + ((4 + kq) ^ (rb & 7)) * 8];
      }
      if (t + 2 < 16) G1_STAGE_B(nxt2, (t + 2) << 6);
      __builtin_amdgcn_s_setprio(1);
      if (isQK) {
#pragma unroll
        for (int fj = 0; fj < 4; fj++)
#pragma unroll
          for (int ti = 0; ti < 4; ti++)
            acc[fj][ti] = __builtin_amdgcn_mfma_f32_16x16x32_bf16(bfr[fj], af[ti], acc[fj][ti], 0, 0, 0);
      } else {
#pragma unroll
        for (int i = 0; i < 4; i++)
#pragma unroll
          for (int j = 0; j < 4; j++)
            acc[i][j] = __builtin_amdgcn_mfma_f32_16x16x32_bf16(af[i], bfr[j], acc[i][j], 0, 0, 0);
      }
      __builtin_amdgcn_s_setprio(0);
    }
    if (t + 2 < 16) {
      asm volatile("s_waitcnt vmcnt(6)" ::: "memory"); // tile t+1 landed
    } else if (t + 1 < 16) {
      asm volatile("s_waitcnt vmcnt(0)" ::: "memory"); // last tile landed
    }
    if (t + 1 < 16) asm volatile("s_barrier" ::: "memory");
    cur = (cur == 2) ? 0 : cur + 1;
    nxt2 = (nxt2 == 2) ? 0 : nxt2 + 1;
  }
#undef G1_STAGE_A
#undef G1_STAGE_B

  const int col = lane & 15, rq = lane >> 4;
  if (isQK) {
    const int qk = tileN >> 10;
    const float* bias = qk ? bK : bQ;
    const int hA = ((tileN & 1023) + wn) >> 5;
    const int d0 = rq * 4;
    const float4 bA0 = *(const float4*)&bias[hA * 32 + d0];
    const float4 bA1 = *(const float4*)&bias[hA * 32 + 16 + d0];
    const float4 bB0 = *(const float4*)&bias[(hA + 1) * 32 + d0];
    const float4 bB1 = *(const float4*)&bias[(hA + 1) * 32 + 16 + d0];
    float invf[4];
#pragma unroll
    for (int r = 0; r < 4; r++)
      invf[r] = exp2f((d0 + r) * -0.8304820237218406f);  // -log2(10000)/16
    const float osc = qk ? 1.f : INV_SCALE_LG2E;  // fold log2(e) into Q scale
#pragma unroll
    for (int ti = 0; ti < 4; ti++) {
      int sg = tileM + wm + ti * 16 + col;
      int s = sg & 1023, bb = sg >> 10;
      float sv[4], cv[4];
#pragma unroll
      for (int r = 0; r < 4; r++) __sincosf((float)s * invf[r], &sv[r], &cv[r]);
#pragma unroll
      for (int p = 0; p < 2; p++) {
        int h = hA + p;
        short4v z0, z1;
#pragma unroll
        for (int r = 0; r < 4; r++) {
          float x0 = acc[2 * p][ti][r]     + (p ? (&bB0.x)[r] : (&bA0.x)[r]);
          float x1 = acc[2 * p + 1][ti][r] + (p ? (&bB1.x)[r] : (&bA1.x)[r]);
          float y0 = (x0 * cv[r] - x1 * sv[r]) * osc;
          float y1 = (x1 * cv[r] + x0 * sv[r]) * osc;
          z0[r] = rnd_bf16(y0); z1[r] = rnd_bf16(y1);
        }
        short* dst = qk
            ? (short*)Kb + ((size_t)(bb * 32 + h) * 1152 + s) * 32
            : (short*)Qb + ((size_t)(bb * 32 + h) * 1024 + s) * 32;
        *(short4v*)(dst + d0) = z0;
        *(short4v*)(dst + 16 + d0) = z1;
      }
    }
  } else {
    const int hv = (tileN - 2048 + wn) >> 6;
#pragma unroll
    for (int i = 0; i < 4; i++)
#pragma unroll
      for (int j = 0; j < 4; j++) {
        int c = j * 16 + col;
        float bias = bV[hv * 64 + c];
        int m0 = tileM + wm + i * 16 + rq * 4;
        int s0 = m0 & 1023, bb = m0 >> 10;
        int chunk = s0 >> 6, w = s0 & 63, u0 = w & 31;
        int p0 = (u0 & 3) | ((u0 & 16) >> 2) | ((u0 & 8) << 1) | ((u0 & 4) << 1);
        int p = (w & 32) | p0;                 // 4-aligned
        int slot = c * 8 + ((p >> 3) ^ (c & 7));
        short4v s4;
#pragma unroll
        for (int r = 0; r < 4; r++) s4[r] = rnd_bf16(acc[i][j][r] + bias);
        *(short4v*)((short*)Vb +
            ((((size_t)(bb * 32 + hv)) * 17 + chunk) * 512 + slot) * 8 + (p & 7)) = s4;
      }
  }
}

// ---- PAIRED-TILE flash attention (R4 structure) + exp2 softmax ------------
// Wave owns q-tiles x and 63-x; K-fragments and V staging shared across both
// chains; V ping-pong LDS staging (coalesced global_load_lds). FIXED-MAX
// softmax: m=0 exact (scores O(0.4)); exp2 via __builtin_amdgcn_exp2f (Q
// carries /sqrt(32)*log2(e)); masked exp2(-1e30)=0. Per-lane partial l,
// one cross-quad reduce at end. setprio(1) around MFMA clusters.
__global__ __launch_bounds__(256) void attn_mfma(
    const bf16* __restrict__ Qb, const bf16* __restrict__ Kb,
    const bf16* __restrict__ Vb, bf16* __restrict__ Zb) {
  __shared__ __align__(16) short Vs[4][2][4096];
  const int flat = blockIdx.x;                 // 0..511
  const int xcd = flat & 7;
  const int hqb = xcd * 8 + ((flat >> 3) & 7);
  const int xb = flat >> 6;                    // 0..7
  const int xblk = (xb < 4) ? xb : (11 - xb);  // pair x with 7-x per CU
  const int hq = hqb & 31, b = hqb >> 5;
  const int wave = threadIdx.x >> 6, lane = threadIdx.x & 63;
  const int col = lane & 15, quad = lane >> 4;
  const int pairIdx = xblk * 4 + wave;         // 0..31
  const int qwA = pairIdx * 16, qwB = (63 - pairIdx) * 16;

  const short* qbase = (const short*)Qb + ((size_t)(b * 32 + hq)) * 1024 * 32;
  const bf16x8 qfA = *(const bf16x8*)(qbase + (qwA + col) * 32 + quad * 8);
  const bf16x8 qfB = *(const bf16x8*)(qbase + (qwB + col) * 32 + quad * 8);
  const short* kbase = (const short*)Kb + ((size_t)(b * 32 + hq)) * 1152 * 32 + quad * 8;
  const short* vbh = (const short*)Vb + ((size_t)(b * 32 + hq)) * (17 * 4096) + lane * 8;

  const int kendA = qwA + 32;
  const int nchA = (kendA + 63) >> 6;
  const int kendB = (qwB + 32 < 1040) ? qwB + 32 : 1040;
  const int nchB = (kendB + 63) >> 6;          // nchA <= nchB

  f32x4 OA[4] = {}, OB[4] = {};
  float lsA = 0.f, lsB = 0.f;                  // per-lane partial softmax sums

  bf16x8 kf[4];
#pragma unroll
  for (int mbk = 0; mbk < 4; mbk++)
    kf[mbk] = *(const bf16x8*)(kbase + (size_t)(mbk * 16 + col) * 32);
  {
    short* vd = &Vs[wave][0][0];
#pragma unroll
    for (int g = 0; g < 8; g++)
      __builtin_amdgcn_global_load_lds(AS1(vbh + g * 512), AS3(vd + g * 512), 16, 0, 0);
  }

  for (int ci = 0; ci < nchB; ci++) {
    const int kc = ci * 64;
    const bool aAct = ci < nchA;
    __builtin_amdgcn_s_setprio(1);
    f32x4 SB[4] = {};
#pragma unroll
    for (int mbk = 0; mbk < 4; mbk++)
      SB[mbk] = __builtin_amdgcn_mfma_f32_16x16x32_bf16(kf[mbk], qfB, SB[mbk], 0, 0, 0);
    f32x4 SA[4] = {};
    if (aAct) {
#pragma unroll
      for (int mbk = 0; mbk < 4; mbk++)
        SA[mbk] = __builtin_amdgcn_mfma_f32_16x16x32_bf16(kf[mbk], qfA, SA[mbk], 0, 0, 0);
    }
    __builtin_amdgcn_s_setprio(0);
    if (kc + 63 > qwB + 16) {
      int qv = qwB + col + 16;
#pragma unroll
      for (int mbk = 0; mbk < 4; mbk++)
#pragma unroll
        for (int r = 0; r < 4; r++)
          if (kc + mbk * 16 + quad * 4 + r > qv) SB[mbk][r] = -1e30f;
    }
    if (aAct && kc + 63 > qwA + 16) {
      int qv = qwA + col + 16;
#pragma unroll
      for (int mbk = 0; mbk < 4; mbk++)
#pragma unroll
        for (int r = 0; r < 4; r++)
          if (kc + mbk * 16 + quad * 4 + r > qv) SA[mbk][r] = -1e30f;
    }
    int4v piB[2], piA[2];
#pragma unroll
    for (int mbk = 0; mbk < 4; mbk++)
#pragma unroll
      for (int r = 0; r < 4; r++) {
        float p = __builtin_amdgcn_exp2f(SB[mbk][r]);
        lsB += p;
        SB[mbk][r] = p;
      }
#pragma unroll
    for (int pr = 0; pr < 2; pr++)
#pragma unroll
      for (int d = 0; d < 4; d++)
        piB[pr][d] = pack_bf16_pair(SB[2 * pr + (d >> 1)][(d & 1) * 2 + 1],
                                    SB[2 * pr + (d >> 1)][(d & 1) * 2]);
    if (aAct) {
#pragma unroll
      for (int mbk = 0; mbk < 4; mbk++)
#pragma unroll
        for (int r = 0; r < 4; r++) {
          float p = __builtin_amdgcn_exp2f(SA[mbk][r]);
          lsA += p;
          SA[mbk][r] = p;
        }
#pragma unroll
      for (int pr = 0; pr < 2; pr++)
#pragma unroll
        for (int d = 0; d < 4; d++)
          piA[pr][d] = pack_bf16_pair(SA[2 * pr + (d >> 1)][(d & 1) * 2 + 1],
                                      SA[2 * pr + (d >> 1)][(d & 1) * 2]);
    }
    asm volatile("s_waitcnt vmcnt(0)" ::: "memory");
    const short* vd = &Vs[wave][ci & 1][0];
    bf16x8 vf[2][4];
#pragma unroll
    for (int ks = 0; ks < 2; ks++)
#pragma unroll
      for (int cb = 0; cb < 4; cb++) {
        int slot = (cb * 16 + col) * 8 + ((ks * 4 + quad) ^ (col & 7));
        vf[ks][cb] = *(const bf16x8*)(vd + slot * 8);
      }
    if (ci + 1 < nchB) {
      const int kn = kc + 64;
#pragma unroll
      for (int mbk = 0; mbk < 4; mbk++)
        kf[mbk] = *(const bf16x8*)(kbase + (size_t)(kn + mbk * 16 + col) * 32);
      const short* vsrc = vbh + (ci + 1) * 4096;
      short* vdn = &Vs[wave][(ci + 1) & 1][0];
#pragma unroll
      for (int g = 0; g < 8; g++)
        __builtin_amdgcn_global_load_lds(AS1(vsrc + g * 512), AS3(vdn + g * 512), 16, 0, 0);
    }
    __builtin_amdgcn_s_setprio(1);
#pragma unroll
    for (int ks = 0; ks < 2; ks++) {
      bf16x8 prB = *(bf16x8*)&piB[ks];
#pragma unroll
      for (int cb = 0; cb < 4; cb++)
        OB[cb] = __builtin_amdgcn_mfma_f32_16x16x32_bf16(vf[ks][cb], prB, OB[cb], 0, 0, 0);
    }
    if (aAct) {
#pragma unroll
      for (int ks = 0; ks < 2; ks++) {
        bf16x8 prA = *(bf16x8*)&piA[ks];
#pragma unroll
        for (int cb = 0; cb < 4; cb++)
          OA[cb] = __builtin_amdgcn_mfma_f32_16x16x32_bf16(vf[ks][cb], prA, OA[cb], 0, 0, 0);
      }
    }
    __builtin_amdgcn_s_setprio(0);
  }
  // cross-quad reduce (lanes ^16, ^32 share the same q-row)
  lsA += __shfl_xor(lsA, 16);
  lsA += __shfl_xor(lsA, 32);
  lsB += __shfl_xor(lsB, 16);
  lsB += __shfl_xor(lsB, 32);
  {
    float inv = 1.f / lsA;
    short* zrow = (short*)Zb + ((size_t)(b * 1024 + qwA + col)) * 2048 + hq * 64 + quad * 4;
#pragma unroll
    for (int cb = 0; cb < 4; cb++) {
      short4v s4;
#pragma unroll
      for (int r = 0; r < 4; r++) s4[r] = rnd_bf16(OA[cb][r] * inv);
      *(short4v*)(zrow + cb * 16) = s4;
    }
  }
  {
    float inv = 1.f / lsB;
    short* zrow = (short*)Zb + ((size_t)(b * 1024 + qwB + col)) * 2048 + hq * 64 + quad * 4;
#pragma unroll
    for (int cb = 0; cb < 4; cb++) {
      short4v s4;
#pragma unroll
      for (int r = 0; r < 4; r++) s4[r] = rnd_bf16(OB[cb][r] * inv);
      *(short4v*)(zrow + cb * 16) = s4;
    }
  }
}

// ---- GEMM2: 64x64 tile, BK=128, double-buffered prefetch, 512 blocks ------
// 1D grid with XCD supertile: xcd owns (xcd>>1)-th M-octet x (xcd&1)-th
// N-octet of the 32x16 tile grid -> per-XCD working set 2MB Zb + 2MB Wot.
// 2-phase pipeline: stage tile t+1 into buf^1 BEFORE computing tile t;
// one __syncthreads per K-step. Compile-time K/ldc + hoisted staging bases.
__global__ __launch_bounds__(256) void gemm2_small(
    const bf16* __restrict__ A, const bf16* __restrict__ Bt, float* __restrict__ C) {
  constexpr int K = 2048, ldc = 1024;
  __shared__ __align__(16) short As[2][64 * 128];
  __shared__ __align__(16) short Bs[2][64 * 128];
  const int flat = blockIdx.x;
  const int xcd = flat & 7, idx = flat >> 3;   // idx 0..63
  const int tileM = ((xcd >> 1) * 8 + (idx & 7)) * 64;   // M octet (32 tiles tot)
  const int tileN = ((xcd & 1) * 8 + (idx >> 3)) * 64;   // N octet (16 tiles tot)
  const int tid = threadIdx.x, wave = tid >> 6, lane = tid & 63;
  const int wm = (wave >> 1) * 32, wn = (wave & 1) * 32;
  const int mrow = lane & 15, kq = lane >> 4;
  f32x4 acc[2][2] = {};

  const int cbase = wave * 4;                  // chunk group base
  const int nt = K >> 7;                       // 16 K-tiles
  const short* gaB[4];
  const short* gbB[4];
#pragma unroll
  for (int i = 0; i < 4; i++) {
    int c = (cbase + i) * 64 + lane;           // chunk 0..1023
    int row = c >> 4, j = c & 15, g = j ^ (row & 15);
    gaB[i] = (const short*)A + (size_t)(tileM + row) * K + g * 8;
    gbB[i] = (const short*)Bt + (size_t)(tileN + row) * K + g * 8;
  }

#define G2_STAGE(buf, k0)                                                     \
  {                                                                           \
    _Pragma("unroll")                                                         \
    for (int i = 0; i < 4; i++) {                                             \
      __builtin_amdgcn_global_load_lds(AS1(gaB[i] + (k0)),                    \
          AS3(&As[buf][(cbase + i) * 512]), 16, 0, 0);                        \
      __builtin_amdgcn_global_load_lds(AS1(gbB[i] + (k0)),                    \
          AS3(&Bs[buf][(cbase + i) * 512]), 16, 0, 0);                        \
    }                                                                         \
  }

  G2_STAGE(0, 0);
  __syncthreads();                             // drains vmcnt(0): buf0 ready
  int cur = 0;
  for (int t = 0; t < nt; ++t) {
    if (t + 1 < nt) G2_STAGE(cur ^ 1, (t + 1) << 7);   // prefetch next tile
    const short* as = &As[cur][0];
    const short* bs = &Bs[cur][0];
#pragma unroll
    for (int ks = 0; ks < 4; ks++) {
      bf16x8 af[2], bfr[2];
#pragma unroll
      for (int t2 = 0; t2 < 2; t2++) {
        int ra = wm + t2 * 16 + mrow, rb = wn + t2 * 16 + mrow;
        af[t2]  = *(const bf16x8*)&as[ra * 128 + ((ks * 4 + kq) ^ (ra & 15)) * 8];
        bfr[t2] = *(const bf16x8*)&bs[rb * 128 + ((ks * 4 + kq) ^ (rb & 15)) * 8];
      }
#pragma unroll
      for (int i = 0; i < 2; i++)
#pragma unroll
        for (int j = 0; j < 2; j++)
          acc[i][j] = __builtin_amdgcn_mfma_f32_16x16x32_bf16(af[i], bfr[j], acc[i][j], 0, 0, 0);
    }
    __syncthreads();                           // next buf ready; cur reusable
    cur ^= 1;
  }
#undef G2_STAGE

  const int col = lane & 15, rq = lane >> 4;
#pragma unroll
  for (int i = 0; i < 2; i++)
#pragma unroll
    for (int j = 0; j < 2; j++)
#pragma unroll
      for (int r = 0; r < 4; r++) {
        int mm = tileM + wm + i * 16 + rq * 4 + r;
        int nn = tileN + wn + j * 16 + col;
        C[(size_t)mm * ldc + nn] = acc[i][j][r];
      }
}

// ---------------------------------------------------------------------------
extern "C" void kernel_launch(void* const* d_in, const int* in_sizes, int n_in,
                              void* d_out, int out_size, void* d_ws, size_t ws_size,
                              hipStream_t stream) {
  const float* resid = (const float*)d_in[0];
  const float* WQ = (const float*)d_in[1];
  const float* WK = (const float*)d_in[2];
  const float* WV = (const float*)d_in[3];
  const float* WO = (const float*)d_in[4];
  const float* bQ = (const float*)d_in[5];
  const float* bK = (const float*)d_in[6];
  const float* bV = (const float*)d_in[7];
  const float* vk = (const float*)d_in[8];
  const float* vv = (const float*)d_in[9];
  float* out = (float*)d_out;

  // workspace layout, no aliasing (~41.5 MB):
  char* ws = (char*)d_ws;
  bf16* A_bf = (bf16*)(ws);                 // 4 MB   [2048][1024]
  bf16* Wt   = (bf16*)(ws + 4194304);       // 8 MB   [4096][1024]
  bf16* Wot  = (bf16*)(ws + 12582912);      // 4 MB   [1024][2048]
  bf16* Qb   = (bf16*)(ws + 16777216);      // 4 MB   [(b,h)][1024][32] scaled
  bf16* Kb   = (bf16*)(ws + 20971520);      // 4.5 MB [(b,h)][1152][32]
  bf16* Vb   = (bf16*)(ws + 25690112);      // 8.5 MB [(b,h)][17][512 slots][8]
  bf16* Zb   = (bf16*)(ws + 35127296);      // 8 MB   [2048][2048]

  prep<<<8704, 256, 0, stream>>>(resid, WV, WQ, WK, WO, vk, vv, A_bf, Wt, Wot, Kb, Vb);
  gemm1_fused<<<256, 512, 0, stream>>>(A_bf, Wt, bQ, bK, bV, Qb, Kb, Vb);
  attn_mfma<<<512, 256, 0, stream>>>(Qb, Kb, Vb, Zb);
  gemm2_small<<<512, 256, 0, stream>>>(Zb, Wot, out);
}

// Round 14
// 150.286 us; speedup vs baseline: 1.0459x; 1.0459x over previous
//
#include <hip/hip_runtime.h>
#include <hip/hip_bf16.h>
#include <math.h>

// ---------------------------------------------------------------------------
// LowRankSparseAttention on MI355X (gfx950)  — best-known configuration
//   (measured 150.88us R11 / 150.97us R12; session floor)
//   1. prep: cvt resid->A_bf, cvt W_V->Wt rows 2048+, virtual K/V fills,
//      transpose W_Q/W_K->Wt, transpose W_O->Wot
//   2. gemm1_fused (128x128 tile, BK=128, swizzled LDS, XCD supertile:
//      8x8 tile block per XCD -> 2MB A + 2MB B fits the 4MB XCD L2):
//      QKV proj + fused epilogue (QK: swapped-operand mfma + rotary,
//      Q scale folds log2(e); V: permuted store).
//      Pipeline lessons (R10 coarse counted-vmcnt +3.6us; R13 fine-phased
//      triple-buffer +6.3us): at this geometry the simple 2-barrier loop
//      with 2 blocks/CU implicit wave overlap is the local optimum; the
//      8-phase template's gains don't transplant partially.
//   3. attn_mfma: PAIRED-TILE flash attn: wave owns tiles x and 63-x,
//      K-fragments + V ping-pong LDS staging shared across chains;
//      FIXED-MAX softmax (m=0 exact, scores O(0.4)); exp2 via
//      __builtin_amdgcn_exp2f; per-lane partial l, one reduce at end.
//   4. gemm2 (64x64 tile, BK=128, double-buffered prefetch, 512 blocks,
//      XCD supertile; compile-time K/ldc + hoisted staging bases).
// 256-B LDS rows alias banks, so staging XOR-swizzles source chunks
// (g = j ^ (row&15)); frag reads un-swizzle -> 2-way conflicts only (free).
// Session note: ~44us of measured dur is the harness's 268MB workspace
// poison fill (75% HBM peak, per-iteration) — irreducible from kernel code.
// ---------------------------------------------------------------------------

typedef short bf16x8 __attribute__((ext_vector_type(8)));
typedef short short4v __attribute__((ext_vector_type(4)));
typedef float f32x4 __attribute__((ext_vector_type(4)));
typedef int int4v __attribute__((ext_vector_type(4)));
typedef __hip_bfloat16 bf16;

#define AS1(p) ((const __attribute__((address_space(1))) void*)(const void*)(p))
#define AS3(p) ((__attribute__((address_space(3))) void*)(void*)(p))

static constexpr float INV_SCALE = 0.17677669529663687f;          // 1/sqrt(32)
static constexpr float INV_SCALE_LG2E =
    0.17677669529663687f * 1.4426950408889634f;                   // /sqrt(32)*log2(e)

// fast RNE f32->bf16 (finite values only): 4 int ops
__device__ inline short rnd_bf16(float x) {
  unsigned u = __float_as_uint(x);
  return (short)((u + 0x7fffu + ((u >> 16) & 1u)) >> 16);
}

// pack two positive f32 -> dword of bf16 pair (round half-up)
__device__ inline int pack_bf16_pair(float hi, float lo) {
  unsigned a = __float_as_uint(hi) + 0x8000u;
  unsigned b = __float_as_uint(lo) + 0x8000u;
  return (int)__builtin_amdgcn_perm(a, b, 0x07060302u);
}

// ---- merged preprocessing kernel ------------------------------------------
__global__ __launch_bounds__(256) void prep(
    const float* __restrict__ resid, const float* __restrict__ WV,
    const float* __restrict__ WQ, const float* __restrict__ WK,
    const float* __restrict__ WO, const float* __restrict__ vk,
    const float* __restrict__ vv,
    bf16* __restrict__ A_bf, bf16* __restrict__ Wt, bf16* __restrict__ Wot,
    bf16* __restrict__ Kb, bf16* __restrict__ Vb) {
  __shared__ float t[64][65];
  const int blk = blockIdx.x, tid = threadIdx.x;
  if (blk < 4096) {
    const float* src = (blk < 2048) ? resid : WV;
    short* dst = (short*)((blk < 2048) ? A_bf : (Wt + (size_t)2048 * 1024));
    int i = ((blk & 2047) * 256 + tid) * 4;
    float4 v = *(const float4*)(src + i);
    dst[i + 0] = rnd_bf16(v.x); dst[i + 1] = rnd_bf16(v.y);
    dst[i + 2] = rnd_bf16(v.z); dst[i + 3] = rnd_bf16(v.w);
  } else if (blk < 7168) {
    int idx = (blk - 4096) * 256 + tid;
    if (idx < 262144) {              // Kb virtual: toks 1024..1151 per (b,h)
      int b = idx >> 17, rem = idx & 131071;
      int j = rem >> 10, c = rem & 1023;     // c = h*32+d
      int h = c >> 5, d = c & 31;
      float v = (j < 16) ? vk[j * 1024 + c] : 0.f;
      Kb[(((size_t)(b * 32 + h)) * 1152 + 1024 + j) * 32 + d] = __float2bfloat16(v);
    } else if (idx < 524288) {       // Vb virtual: chunk 16 (toks 1024..1087)
      int i2 = idx - 262144;         // [0, 262144): 2 b x 2048 ch x 64 p
      int b = i2 >> 17, rem = i2 & 131071;
      int ch = rem >> 6, p = rem & 63;
      int pl = p & 31;
      int u = (p & 32) | ((pl & 4) << 2) | ((pl & 24) >> 1) | (pl & 3);
      float v = (u < 16) ? vv[(size_t)u * 2048 + ch] : 0.f;
      int hv = ch >> 6, c = ch & 63;
      int slot = c * 8 + ((p >> 3) ^ (c & 7));
      Vb[((((size_t)(b * 32 + hv)) * 17 + 16) * 512 + slot) * 8 + (p & 7)] = __float2bfloat16(v);
    }
  } else if (blk < 8192) {
    int i = blk - 7168;
    int mt = i & 15, h = (i >> 4) & 31, qk = i >> 9;
    const float* W = qk ? WK : WQ;
    const int m0 = mt * 64;
    for (int idx = tid; idx < 64 * 32; idx += 256) {
      int ii = idx >> 5, d = idx & 31;
      t[ii][d] = W[((size_t)h * 1024 + m0 + ii) * 32 + d];
    }
    __syncthreads();
    const int rowbase = qk * 1024 + h * 32;
    for (int idx = tid; idx < 32 * 64; idx += 256) {
      int d = idx >> 6, ii = idx & 63;
      Wt[(size_t)(rowbase + d) * 1024 + m0 + ii] = __float2bfloat16(t[ii][d]);
    }
  } else {
    int i = blk - 8192;
    int h0 = (i & 31) * 64, m0 = (i >> 5) * 64;
    for (int idx = tid; idx < 64 * 64; idx += 256) {
      int ii = idx >> 6, j = idx & 63;
      t[ii][j] = WO[(size_t)(h0 + ii) * 1024 + m0 + j];
    }
    __syncthreads();
    for (int idx = tid; idx < 64 * 64; idx += 256) {
      int ii = idx >> 6, j = idx & 63;
      Wot[(size_t)(m0 + ii) * 2048 + h0 + j] = __float2bfloat16(t[j][ii]);
    }
  }
}

// ---- GEMM1 + fused epilogue: 128x128 tile, BK=128, K=1024 -----------------
// LDS: [128 rows][128 cols] bf16, 16 chunks(16B)/row; LDS pos (row,j) holds
// global chunk j^(row&15). Frag read un-swizzles. 8 K-iters, 64 mfma/iter.
// XCD supertile: xcd owns (xcd>>2)-th M-octet x (xcd&3)-th N-octet:
// per-XCD co-resident working set = 2MB A + 2MB B -> fits 4MB XCD L2.
__global__ __launch_bounds__(256) void gemm1_fused(
    const bf16* __restrict__ A, const bf16* __restrict__ Bt,
    const float* __restrict__ bQ, const float* __restrict__ bK,
    const float* __restrict__ bV,
    bf16* __restrict__ Qb, bf16* __restrict__ Kb, bf16* __restrict__ Vb) {
  __shared__ __align__(16) short As[128 * 128];
  __shared__ __align__(16) short Bs[128 * 128];
  const int flat = blockIdx.x;
  const int xcd = flat & 7, idx = flat >> 3;          // idx 0..63
  const int tileM = ((xcd >> 2) * 8 + (idx & 7)) * 128;   // M octet per xcd-half
  const int tileN = ((xcd & 3) * 8 + (idx >> 3)) * 128;   // N octet per xcd-quarter
  const int tid = threadIdx.x, wave = tid >> 6, lane = tid & 63;
  const int wm = (wave >> 1) * 64, wn = (wave & 1) * 64;
  const int mrow = lane & 15, kq = lane >> 4;
  const bool isQK = tileN < 2048;
  f32x4 acc[4][4] = {};

  for (int k0 = 0; k0 < 1024; k0 += 128) {
#pragma unroll
    for (int i = 0; i < 8; i++) {
      int c = (wave * 8 + i) * 64 + lane;          // chunk 0..2047
      int row = c >> 4, j = c & 15, g = j ^ (row & 15);
      const short* ga = (const short*)A + (size_t)(tileM + row) * 1024 + k0 + g * 8;
      const short* gb = (const short*)Bt + (size_t)(tileN + row) * 1024 + k0 + g * 8;
      __builtin_amdgcn_global_load_lds(AS1(ga), AS3(&As[(wave * 8 + i) * 512]), 16, 0, 0);
      __builtin_amdgcn_global_load_lds(AS1(gb), AS3(&Bs[(wave * 8 + i) * 512]), 16, 0, 0);
    }
    __syncthreads();
#pragma unroll
    for (int ks = 0; ks < 4; ks++) {
      bf16x8 af[4], bfr[4];
#pragma unroll
      for (int t = 0; t < 4; t++) {
        int ra = wm + t * 16 + mrow, rb = wn + t * 16 + mrow;
        af[t]  = *(const bf16x8*)&As[ra * 128 + ((ks * 4 + kq) ^ (ra & 15)) * 8];
        bfr[t] = *(const bf16x8*)&Bs[rb * 128 + ((ks * 4 + kq) ^ (rb & 15)) * 8];
      }
      if (isQK) {
#pragma unroll
        for (int fj = 0; fj < 4; fj++)
#pragma unroll
          for (int ti = 0; ti < 4; ti++)
            acc[fj][ti] = __builtin_amdgcn_mfma_f32_16x16x32_bf16(bfr[fj], af[ti], acc[fj][ti], 0, 0, 0);
      } else {
#pragma unroll
        for (int i = 0; i < 4; i++)
#pragma unroll
          for (int j = 0; j < 4; j++)
            acc[i][j] = __builtin_amdgcn_mfma_f32_16x16x32_bf16(af[i], bfr[j], acc[i][j], 0, 0, 0);
      }
    }
    __syncthreads();
  }

  const int col = lane & 15, rq = lane >> 4;
  if (isQK) {
    const int qk = tileN >> 10;
    const float* bias = qk ? bK : bQ;
    const int hA = ((tileN & 1023) + wn) >> 5;
    const int d0 = rq * 4;
    const float4 bA0 = *(const float4*)&bias[hA * 32 + d0];
    const float4 bA1 = *(const float4*)&bias[hA * 32 + 16 + d0];
    const float4 bB0 = *(const float4*)&bias[(hA + 1) * 32 + d0];
    const float4 bB1 = *(const float4*)&bias[(hA + 1) * 32 + 16 + d0];
    float invf[4];
#pragma unroll
    for (int r = 0; r < 4; r++)
      invf[r] = exp2f((d0 + r) * -0.8304820237218406f);  // -log2(10000)/16
    const float osc = qk ? 1.f : INV_SCALE_LG2E;  // fold log2(e) into Q scale
#pragma unroll
    for (int ti = 0; ti < 4; ti++) {
      int sg = tileM + wm + ti * 16 + col;
      int s = sg & 1023, bb = sg >> 10;
      float sv[4], cv[4];
#pragma unroll
      for (int r = 0; r < 4; r++) __sincosf((float)s * invf[r], &sv[r], &cv[r]);
#pragma unroll
      for (int p = 0; p < 2; p++) {
        int h = hA + p;
        short4v z0, z1;
#pragma unroll
        for (int r = 0; r < 4; r++) {
          float x0 = acc[2 * p][ti][r]     + (p ? (&bB0.x)[r] : (&bA0.x)[r]);
          float x1 = acc[2 * p + 1][ti][r] + (p ? (&bB1.x)[r] : (&bA1.x)[r]);
          float y0 = (x0 * cv[r] - x1 * sv[r]) * osc;
          float y1 = (x1 * cv[r] + x0 * sv[r]) * osc;
          z0[r] = rnd_bf16(y0); z1[r] = rnd_bf16(y1);
        }
        short* dst = qk
            ? (short*)Kb + ((size_t)(bb * 32 + h) * 1152 + s) * 32
            : (short*)Qb + ((size_t)(bb * 32 + h) * 1024 + s) * 32;
        *(short4v*)(dst + d0) = z0;
        *(short4v*)(dst + 16 + d0) = z1;
      }
    }
  } else {
    const int hv = (tileN - 2048 + wn) >> 6;
#pragma unroll
    for (int i = 0; i < 4; i++)
#pragma unroll
      for (int j = 0; j < 4; j++) {
        int c = j * 16 + col;
        float bias = bV[hv * 64 + c];
        int m0 = tileM + wm + i * 16 + rq * 4;
        int s0 = m0 & 1023, bb = m0 >> 10;
        int chunk = s0 >> 6, w = s0 & 63, u0 = w & 31;
        int p0 = (u0 & 3) | ((u0 & 16) >> 2) | ((u0 & 8) << 1) | ((u0 & 4) << 1);
        int p = (w & 32) | p0;                 // 4-aligned
        int slot = c * 8 + ((p >> 3) ^ (c & 7));
        short4v s4;
#pragma unroll
        for (int r = 0; r < 4; r++) s4[r] = rnd_bf16(acc[i][j][r] + bias);
        *(short4v*)((short*)Vb +
            ((((size_t)(bb * 32 + hv)) * 17 + chunk) * 512 + slot) * 8 + (p & 7)) = s4;
      }
  }
}

// ---- PAIRED-TILE flash attention (R4 structure) + exp2 softmax ------------
// Wave owns q-tiles x and 63-x; K-fragments and V staging shared across both
// chains; V ping-pong LDS staging (coalesced global_load_lds). FIXED-MAX
// softmax: m=0 exact (scores O(0.4)); exp2 via __builtin_amdgcn_exp2f (Q
// carries /sqrt(32)*log2(e)); masked exp2(-1e30)=0. Per-lane partial l,
// one cross-quad reduce at end. setprio(1) around MFMA clusters.
__global__ __launch_bounds__(256) void attn_mfma(
    const bf16* __restrict__ Qb, const bf16* __restrict__ Kb,
    const bf16* __restrict__ Vb, bf16* __restrict__ Zb) {
  __shared__ __align__(16) short Vs[4][2][4096];
  const int flat = blockIdx.x;                 // 0..511
  const int xcd = flat & 7;
  const int hqb = xcd * 8 + ((flat >> 3) & 7);
  const int xb = flat >> 6;                    // 0..7
  const int xblk = (xb < 4) ? xb : (11 - xb);  // pair x with 7-x per CU
  const int hq = hqb & 31, b = hqb >> 5;
  const int wave = threadIdx.x >> 6, lane = threadIdx.x & 63;
  const int col = lane & 15, quad = lane >> 4;
  const int pairIdx = xblk * 4 + wave;         // 0..31
  const int qwA = pairIdx * 16, qwB = (63 - pairIdx) * 16;

  const short* qbase = (const short*)Qb + ((size_t)(b * 32 + hq)) * 1024 * 32;
  const bf16x8 qfA = *(const bf16x8*)(qbase + (qwA + col) * 32 + quad * 8);
  const bf16x8 qfB = *(const bf16x8*)(qbase + (qwB + col) * 32 + quad * 8);
  const short* kbase = (const short*)Kb + ((size_t)(b * 32 + hq)) * 1152 * 32 + quad * 8;
  const short* vbh = (const short*)Vb + ((size_t)(b * 32 + hq)) * (17 * 4096) + lane * 8;

  const int kendA = qwA + 32;
  const int nchA = (kendA + 63) >> 6;
  const int kendB = (qwB + 32 < 1040) ? qwB + 32 : 1040;
  const int nchB = (kendB + 63) >> 6;          // nchA <= nchB

  f32x4 OA[4] = {}, OB[4] = {};
  float lsA = 0.f, lsB = 0.f;                  // per-lane partial softmax sums

  bf16x8 kf[4];
#pragma unroll
  for (int mbk = 0; mbk < 4; mbk++)
    kf[mbk] = *(const bf16x8*)(kbase + (size_t)(mbk * 16 + col) * 32);
  {
    short* vd = &Vs[wave][0][0];
#pragma unroll
    for (int g = 0; g < 8; g++)
      __builtin_amdgcn_global_load_lds(AS1(vbh + g * 512), AS3(vd + g * 512), 16, 0, 0);
  }

  for (int ci = 0; ci < nchB; ci++) {
    const int kc = ci * 64;
    const bool aAct = ci < nchA;
    __builtin_amdgcn_s_setprio(1);
    f32x4 SB[4] = {};
#pragma unroll
    for (int mbk = 0; mbk < 4; mbk++)
      SB[mbk] = __builtin_amdgcn_mfma_f32_16x16x32_bf16(kf[mbk], qfB, SB[mbk], 0, 0, 0);
    f32x4 SA[4] = {};
    if (aAct) {
#pragma unroll
      for (int mbk = 0; mbk < 4; mbk++)
        SA[mbk] = __builtin_amdgcn_mfma_f32_16x16x32_bf16(kf[mbk], qfA, SA[mbk], 0, 0, 0);
    }
    __builtin_amdgcn_s_setprio(0);
    if (kc + 63 > qwB + 16) {
      int qv = qwB + col + 16;
#pragma unroll
      for (int mbk = 0; mbk < 4; mbk++)
#pragma unroll
        for (int r = 0; r < 4; r++)
          if (kc + mbk * 16 + quad * 4 + r > qv) SB[mbk][r] = -1e30f;
    }
    if (aAct && kc + 63 > qwA + 16) {
      int qv = qwA + col + 16;
#pragma unroll
      for (int mbk = 0; mbk < 4; mbk++)
#pragma unroll
        for (int r = 0; r < 4; r++)
          if (kc + mbk * 16 + quad * 4 + r > qv) SA[mbk][r] = -1e30f;
    }
    int4v piB[2], piA[2];
#pragma unroll
    for (int mbk = 0; mbk < 4; mbk++)
#pragma unroll
      for (int r = 0; r < 4; r++) {
        float p = __builtin_amdgcn_exp2f(SB[mbk][r]);
        lsB += p;
        SB[mbk][r] = p;
      }
#pragma unroll
    for (int pr = 0; pr < 2; pr++)
#pragma unroll
      for (int d = 0; d < 4; d++)
        piB[pr][d] = pack_bf16_pair(SB[2 * pr + (d >> 1)][(d & 1) * 2 + 1],
                                    SB[2 * pr + (d >> 1)][(d & 1) * 2]);
    if (aAct) {
#pragma unroll
      for (int mbk = 0; mbk < 4; mbk++)
#pragma unroll
        for (int r = 0; r < 4; r++) {
          float p = __builtin_amdgcn_exp2f(SA[mbk][r]);
          lsA += p;
          SA[mbk][r] = p;
        }
#pragma unroll
      for (int pr = 0; pr < 2; pr++)
#pragma unroll
        for (int d = 0; d < 4; d++)
          piA[pr][d] = pack_bf16_pair(SA[2 * pr + (d >> 1)][(d & 1) * 2 + 1],
                                      SA[2 * pr + (d >> 1)][(d & 1) * 2]);
    }
    asm volatile("s_waitcnt vmcnt(0)" ::: "memory");
    const short* vd = &Vs[wave][ci & 1][0];
    bf16x8 vf[2][4];
#pragma unroll
    for (int ks = 0; ks < 2; ks++)
#pragma unroll
      for (int cb = 0; cb < 4; cb++) {
        int slot = (cb * 16 + col) * 8 + ((ks * 4 + quad) ^ (col & 7));
        vf[ks][cb] = *(const bf16x8*)(vd + slot * 8);
      }
    if (ci + 1 < nchB) {
      const int kn = kc + 64;
#pragma unroll
      for (int mbk = 0; mbk < 4; mbk++)
        kf[mbk] = *(const bf16x8*)(kbase + (size_t)(kn + mbk * 16 + col) * 32);
      const short* vsrc = vbh + (ci + 1) * 4096;
      short* vdn = &Vs[wave][(ci + 1) & 1][0];
#pragma unroll
      for (int g = 0; g < 8; g++)
        __builtin_amdgcn_global_load_lds(AS1(vsrc + g * 512), AS3(vdn + g * 512), 16, 0, 0);
    }
    __builtin_amdgcn_s_setprio(1);
#pragma unroll
    for (int ks = 0; ks < 2; ks++) {
      bf16x8 prB = *(bf16x8*)&piB[ks];
#pragma unroll
      for (int cb = 0; cb < 4; cb++)
        OB[cb] = __builtin_amdgcn_mfma_f32_16x16x32_bf16(vf[ks][cb], prB, OB[cb], 0, 0, 0);
    }
    if (aAct) {
#pragma unroll
      for (int ks = 0; ks < 2; ks++) {
        bf16x8 prA = *(bf16x8*)&piA[ks];
#pragma unroll
        for (int cb = 0; cb < 4; cb++)
          OA[cb] = __builtin_amdgcn_mfma_f32_16x16x32_bf16(vf[ks][cb], prA, OA[cb], 0, 0, 0);
      }
    }
    __builtin_amdgcn_s_setprio(0);
  }
  // cross-quad reduce (lanes ^16, ^32 share the same q-row)
  lsA += __shfl_xor(lsA, 16);
  lsA += __shfl_xor(lsA, 32);
  lsB += __shfl_xor(lsB, 16);
  lsB += __shfl_xor(lsB, 32);
  {
    float inv = 1.f / lsA;
    short* zrow = (short*)Zb + ((size_t)(b * 1024 + qwA + col)) * 2048 + hq * 64 + quad * 4;
#pragma unroll
    for (int cb = 0; cb < 4; cb++) {
      short4v s4;
#pragma unroll
      for (int r = 0; r < 4; r++) s4[r] = rnd_bf16(OA[cb][r] * inv);
      *(short4v*)(zrow + cb * 16) = s4;
    }
  }
  {
    float inv = 1.f / lsB;
    short* zrow = (short*)Zb + ((size_t)(b * 1024 + qwB + col)) * 2048 + hq * 64 + quad * 4;
#pragma unroll
    for (int cb = 0; cb < 4; cb++) {
      short4v s4;
#pragma unroll
      for (int r = 0; r < 4; r++) s4[r] = rnd_bf16(OB[cb][r] * inv);
      *(short4v*)(zrow + cb * 16) = s4;
    }
  }
}

// ---- GEMM2: 64x64 tile, BK=128, double-buffered prefetch, 512 blocks ------
// 1D grid with XCD supertile: xcd owns (xcd>>1)-th M-octet x (xcd&1)-th
// N-octet of the 32x16 tile grid -> per-XCD working set 2MB Zb + 2MB Wot.
// 2-phase pipeline: stage tile t+1 into buf^1 BEFORE computing tile t;
// one __syncthreads per K-step. Compile-time K/ldc + hoisted staging bases.
__global__ __launch_bounds__(256) void gemm2_small(
    const bf16* __restrict__ A, const bf16* __restrict__ Bt, float* __restrict__ C) {
  constexpr int K = 2048, ldc = 1024;
  __shared__ __align__(16) short As[2][64 * 128];
  __shared__ __align__(16) short Bs[2][64 * 128];
  const int flat = blockIdx.x;
  const int xcd = flat & 7, idx = flat >> 3;   // idx 0..63
  const int tileM = ((xcd >> 1) * 8 + (idx & 7)) * 64;   // M octet (32 tiles tot)
  const int tileN = ((xcd & 1) * 8 + (idx >> 3)) * 64;   // N octet (16 tiles tot)
  const int tid = threadIdx.x, wave = tid >> 6, lane = tid & 63;
  const int wm = (wave >> 1) * 32, wn = (wave & 1) * 32;
  const int mrow = lane & 15, kq = lane >> 4;
  f32x4 acc[2][2] = {};

  const int cbase = wave * 4;                  // chunk group base
  const int nt = K >> 7;                       // 16 K-tiles
  const short* gaB[4];
  const short* gbB[4];
#pragma unroll
  for (int i = 0; i < 4; i++) {
    int c = (cbase + i) * 64 + lane;           // chunk 0..1023
    int row = c >> 4, j = c & 15, g = j ^ (row & 15);
    gaB[i] = (const short*)A + (size_t)(tileM + row) * K + g * 8;
    gbB[i] = (const short*)Bt + (size_t)(tileN + row) * K + g * 8;
  }

#define G2_STAGE(buf, k0)                                                     \
  {                                                                           \
    _Pragma("unroll")                                                         \
    for (int i = 0; i < 4; i++) {                                             \
      __builtin_amdgcn_global_load_lds(AS1(gaB[i] + (k0)),                    \
          AS3(&As[buf][(cbase + i) * 512]), 16, 0, 0);                        \
      __builtin_amdgcn_global_load_lds(AS1(gbB[i] + (k0)),                    \
          AS3(&Bs[buf][(cbase + i) * 512]), 16, 0, 0);                        \
    }                                                                         \
  }

  G2_STAGE(0, 0);
  __syncthreads();                             // drains vmcnt(0): buf0 ready
  int cur = 0;
  for (int t = 0; t < nt; ++t) {
    if (t + 1 < nt) G2_STAGE(cur ^ 1, (t + 1) << 7);   // prefetch next tile
    const short* as = &As[cur][0];
    const short* bs = &Bs[cur][0];
#pragma unroll
    for (int ks = 0; ks < 4; ks++) {
      bf16x8 af[2], bfr[2];
#pragma unroll
      for (int t2 = 0; t2 < 2; t2++) {
        int ra = wm + t2 * 16 + mrow, rb = wn + t2 * 16 + mrow;
        af[t2]  = *(const bf16x8*)&as[ra * 128 + ((ks * 4 + kq) ^ (ra & 15)) * 8];
        bfr[t2] = *(const bf16x8*)&bs[rb * 128 + ((ks * 4 + kq) ^ (rb & 15)) * 8];
      }
#pragma unroll
      for (int i = 0; i < 2; i++)
#pragma unroll
        for (int j = 0; j < 2; j++)
          acc[i][j] = __builtin_amdgcn_mfma_f32_16x16x32_bf16(af[i], bfr[j], acc[i][j], 0, 0, 0);
    }
    __syncthreads();                           // next buf ready; cur reusable
    cur ^= 1;
  }
#undef G2_STAGE

  const int col = lane & 15, rq = lane >> 4;
#pragma unroll
  for (int i = 0; i < 2; i++)
#pragma unroll
    for (int j = 0; j < 2; j++)
#pragma unroll
      for (int r = 0; r < 4; r++) {
        int mm = tileM + wm + i * 16 + rq * 4 + r;
        int nn = tileN + wn + j * 16 + col;
        C[(size_t)mm * ldc + nn] = acc[i][j][r];
      }
}

// ---------------------------------------------------------------------------
extern "C" void kernel_launch(void* const* d_in, const int* in_sizes, int n_in,
                              void* d_out, int out_size, void* d_ws, size_t ws_size,
                              hipStream_t stream) {
  const float* resid = (const float*)d_in[0];
  const float* WQ = (const float*)d_in[1];
  const float* WK = (const float*)d_in[2];
  const float* WV = (const float*)d_in[3];
  const float* WO = (const float*)d_in[4];
  const float* bQ = (const float*)d_in[5];
  const float* bK = (const float*)d_in[6];
  const float* bV = (const float*)d_in[7];
  const float* vk = (const float*)d_in[8];
  const float* vv = (const float*)d_in[9];
  float* out = (float*)d_out;

  // workspace layout, no aliasing (~41.5 MB):
  char* ws = (char*)d_ws;
  bf16* A_bf = (bf16*)(ws);                 // 4 MB   [2048][1024]
  bf16* Wt   = (bf16*)(ws + 4194304);       // 8 MB   [4096][1024]
  bf16* Wot  = (bf16*)(ws + 12582912);      // 4 MB   [1024][2048]
  bf16* Qb   = (bf16*)(ws + 16777216);      // 4 MB   [(b,h)][1024][32] scaled
  bf16* Kb   = (bf16*)(ws + 20971520);      // 4.5 MB [(b,h)][1152][32]
  bf16* Vb   = (bf16*)(ws + 25690112);      // 8.5 MB [(b,h)][17][512 slots][8]
  bf16* Zb   = (bf16*)(ws + 35127296);      // 8 MB   [2048][2048]

  prep<<<8704, 256, 0, stream>>>(resid, WV, WQ, WK, WO, vk, vv, A_bf, Wt, Wot, Kb, Vb);
  gemm1_fused<<<512, 256, 0, stream>>>(A_bf, Wt, bQ, bK, bV, Qb, Kb, Vb);
  attn_mfma<<<512, 256, 0, stream>>>(Qb, Kb, Vb, Zb);
  gemm2_small<<<512, 256, 0, stream>>>(Zb, Wot, out);
}